// Round 14
// baseline (72.331 us; speedup 1.0000x reference)
//
#include <hip/hip_runtime.h>
#include <hip/hip_fp16.h>

// Mixture-of-64-tiny-experts.
// R13: packed-f16 rate experiment. R12 structure (2 samples/thread, subnet-
// pair packing, wave-uniform s_load weights) but L1 + activations + L2 run in
// __half2 (v_pk_*_f16, full-rate 2cyc vs pk_f32 4cyc; v_rcp_f16 is f16-exact
// so the NR step disappears). Gate path (logits, exp2, softmax accum) stays
// f32 for precision. f16 exp2 overflow -> inf -> rcp -> 0 = correct tanh
// saturation (graceful).

#define NSUB 64
#define L2E  1.4426950408889634f   // log2(e)
#define L2E2 2.8853900817779268f   // 2*log2(e)

typedef float v2f __attribute__((ext_vector_type(2)));

__device__ __forceinline__ v2f pk_fma(v2f a, v2f b, v2f c) {
    return __builtin_elementwise_fma(a, b, c);
}
__device__ __forceinline__ v2f sp(float s) { return v2f{s, s}; }

// f16x2 tanhshrink(a) = (a-1) + 2*rcp(exp2(2L*a)+1)
__device__ __forceinline__ __half2 tanhshrink_h2(__half2 a, __half2 c2l2,
                                                 __half2 one, __half2 two) {
    __half2 m = __hmul2(a, c2l2);
    __half2 e = __halves2half2(hexp2(__low2half(m)), hexp2(__high2half(m)));
    __half2 ep = __hadd2(e, one);
    __half2 r = __halves2half2(hrcp(__low2half(ep)), hrcp(__high2half(ep)));
    return __hfma2(two, r, __hsub2(a, one));
}

// f16x2 tanh from pre-scaled input s = 2L*raw: 1 - 2*rcp(exp2(s)+1)
__device__ __forceinline__ __half2 tanh_scaled_h2(__half2 s, __half2 one,
                                                  __half2 neg2) {
    __half2 e = __halves2half2(hexp2(__low2half(s)), hexp2(__high2half(s)));
    __half2 ep = __hadd2(e, one);
    __half2 r = __halves2half2(hrcp(__low2half(ep)), hrcp(__high2half(ep)));
    return __hfma2(neg2, r, one);
}

// scalar f32 tanhshrink for the gating net
__device__ __forceinline__ float tanhshrink_s(float a) {
    float e = __builtin_amdgcn_exp2f(a * L2E2);
    float r = __builtin_amdgcn_rcpf(e + 1.0f);
    return fmaf(2.0f, r, a - 1.0f);
}

// Pack layout per subnet-pair p (subnets p, p+32):
//  __half2 region (index base p*40):
//   [0:24)  W1 pairs (j*6+i)      [24:28) b1 pairs
//   [28:36) W2*2L pairs (o*4+j)   [36:38) b2*2L pairs   [38:40) pad
//  f32 v2f region at float offset 1280 (base p*16 floats = 8 v2f):
//   [0:6) Gw2*L pairs  [6] Gb2*L pair  [7] pad
__global__ void pack_kernel(const float* __restrict__ W1, const float* __restrict__ b1,
                            const float* __restrict__ W2, const float* __restrict__ b2,
                            const float* __restrict__ Gw2, const float* __restrict__ Gb2,
                            float* __restrict__ ws)
{
    int p = threadIdx.x;
    if (p >= 32) return;
    int sa = p, sb = p + 32;
    __half2* h = ((__half2*)ws) + p * 40;
    for (int i = 0; i < 24; ++i)
        h[i] = __halves2half2(__float2half(W1[sa*24+i]), __float2half(W1[sb*24+i]));
    for (int i = 0; i < 4; ++i)
        h[24+i] = __halves2half2(__float2half(b1[sa*4+i]), __float2half(b1[sb*4+i]));
    for (int i = 0; i < 8; ++i)
        h[28+i] = __halves2half2(__float2half(W2[sa*8+i]*L2E2), __float2half(W2[sb*8+i]*L2E2));
    for (int i = 0; i < 2; ++i)
        h[36+i] = __halves2half2(__float2half(b2[sa*2+i]*L2E2), __float2half(b2[sb*2+i]*L2E2));
    h[38] = __halves2half2(__float2half(0.f), __float2half(0.f));
    h[39] = h[38];

    float* g = ws + 1280 + p * 16;
    for (int i = 0; i < 6; ++i) { g[2*i] = Gw2[sa*6+i]*L2E; g[2*i+1] = Gw2[sb*6+i]*L2E; }
    g[12] = Gb2[sa]*L2E; g[13] = Gb2[sb]*L2E;
    g[14] = 0.f; g[15] = 0.f;
}

__global__ __launch_bounds__(256) void moe_kernel(
    const float* __restrict__ x,
    const float* __restrict__ wpack,
    const float* __restrict__ Gw1, const float* __restrict__ Gb1,
    float* __restrict__ out)
{
    long t = blockIdx.x * blockDim.x + threadIdx.x;

    const __half2 c2l2 = __float2half2_rn(L2E2);
    const __half2 one  = __float2half2_rn(1.0f);
    const __half2 two  = __float2half2_rn(2.0f);
    const __half2 neg2 = __float2half2_rn(-2.0f);

    // two samples per thread: 12 floats = 3 x float4
    const float4* xv = (const float4*)(x + t * 12);
    float4 q0 = xv[0];
    float4 q1 = xv[1];
    float4 q2 = xv[2];
    float xsA[6] = {q0.x, q0.y, q0.z, q0.w, q1.x, q1.y};
    float xsB[6] = {q1.z, q1.w, q2.x, q2.y, q2.z, q2.w};

    // ---- gating hidden per sample (scalar f32) ----
    float gaA[6], gaB[6];
#pragma unroll
    for (int j = 0; j < 6; ++j) {
        float sA = Gb1[j], sB = sA;
#pragma unroll
        for (int i = 0; i < 6; ++i) {
            float w = Gw1[j * 6 + i];
            sA = fmaf(w, xsA[i], sA);
            sB = fmaf(w, xsB[i], sB);
        }
        gaA[j] = tanhshrink_s(sA);
        gaB[j] = tanhshrink_s(sB);
    }

    // f16 broadcast of sample values (halves = subnet pair, same sample)
    __half2 xhA[6], xhB[6];
#pragma unroll
    for (int i = 0; i < 6; ++i) {
        xhA[i] = __float2half2_rn(xsA[i]);
        xhB[i] = __float2half2_rn(xsB[i]);
    }
    // f32 gate-hidden broadcast
    v2f gbA[6], gbB[6];
#pragma unroll
    for (int j = 0; j < 6; ++j) { gbA[j] = sp(gaA[j]); gbB[j] = sp(gaB[j]); }

    v2f acc0A = sp(0.f), acc1A = sp(0.f), accEA = sp(0.f);
    v2f acc0B = sp(0.f), acc1B = sp(0.f), accEB = sp(0.f);

#pragma unroll 2
    for (int p = 0; p < 32; ++p) {
        const __half2* fh = ((const __half2*)wpack) + p * 40;
        const v2f* g2 = (const v2f*)(wpack + 1280 + p * 16);

        // ---- layer 1 (f16x2) ----
        __half2 hA[4], hB[4];
#pragma unroll
        for (int j = 0; j < 4; ++j) {
            __half2 bb = fh[24 + j];
            __half2 sA = __hfma2(fh[j * 6 + 0], xhA[0], bb);
            __half2 sB = __hfma2(fh[j * 6 + 0], xhB[0], bb);
#pragma unroll
            for (int i = 1; i < 6; ++i) {
                __half2 w = fh[j * 6 + i];
                sA = __hfma2(w, xhA[i], sA);
                sB = __hfma2(w, xhB[i], sB);
            }
            hA[j] = tanhshrink_h2(sA, c2l2, one, two);
            hB[j] = tanhshrink_h2(sB, c2l2, one, two);
        }

        // ---- layer 2 (f16x2, weights pre-scaled by 2*log2e) ----
        __half2 o0A = __hfma2(fh[28], hA[0], fh[36]);
        __half2 o0B = __hfma2(fh[28], hB[0], fh[36]);
        o0A = __hfma2(fh[29], hA[1], o0A);  o0B = __hfma2(fh[29], hB[1], o0B);
        o0A = __hfma2(fh[30], hA[2], o0A);  o0B = __hfma2(fh[30], hB[2], o0B);
        o0A = __hfma2(fh[31], hA[3], o0A);  o0B = __hfma2(fh[31], hB[3], o0B);
        __half2 t0A = tanh_scaled_h2(o0A, one, neg2);
        __half2 t0B = tanh_scaled_h2(o0B, one, neg2);

        __half2 o1A = __hfma2(fh[32], hA[0], fh[37]);
        __half2 o1B = __hfma2(fh[32], hB[0], fh[37]);
        o1A = __hfma2(fh[33], hA[1], o1A);  o1B = __hfma2(fh[33], hB[1], o1B);
        o1A = __hfma2(fh[34], hA[2], o1A);  o1B = __hfma2(fh[34], hB[2], o1B);
        o1A = __hfma2(fh[35], hA[3], o1A);  o1B = __hfma2(fh[35], hB[3], o1B);
        __half2 t1A = tanh_scaled_h2(o1A, one, neg2);
        __half2 t1B = tanh_scaled_h2(o1B, one, neg2);

        // ---- gate logit (f32 pk; weights pre-scaled by log2e) ----
        v2f laA = pk_fma(g2[0], gbA[0], g2[6]);
        v2f laB = pk_fma(g2[0], gbB[0], g2[6]);
        laA = pk_fma(g2[1], gbA[1], laA);  laB = pk_fma(g2[1], gbB[1], laB);
        laA = pk_fma(g2[2], gbA[2], laA);  laB = pk_fma(g2[2], gbB[2], laB);
        laA = pk_fma(g2[3], gbA[3], laA);  laB = pk_fma(g2[3], gbB[3], laB);
        laA = pk_fma(g2[4], gbA[4], laA);  laB = pk_fma(g2[4], gbB[4], laB);
        laA = pk_fma(g2[5], gbA[5], laA);  laB = pk_fma(g2[5], gbB[5], laB);

        v2f eA, eB;
        eA.x = __builtin_amdgcn_exp2f(laA.x);
        eA.y = __builtin_amdgcn_exp2f(laA.y);
        eB.x = __builtin_amdgcn_exp2f(laB.x);
        eB.y = __builtin_amdgcn_exp2f(laB.y);

        // ---- f32 accumulation (f16 -> f32 converts) ----
        float2 f0A = __half22float2(t0A), f1A = __half22float2(t1A);
        float2 f0B = __half22float2(t0B), f1B = __half22float2(t1B);

        accEA = accEA + eA;                          accEB = accEB + eB;
        acc0A = pk_fma(eA, v2f{f0A.x, f0A.y}, acc0A);
        acc0B = pk_fma(eB, v2f{f0B.x, f0B.y}, acc0B);
        acc1A = pk_fma(eA, v2f{f1A.x, f1A.y}, acc1A);
        acc1B = pk_fma(eB, v2f{f1B.x, f1B.y}, acc1B);
    }

    float EA = accEA.x + accEA.y;
    float EB = accEB.x + accEB.y;
    float rA = __builtin_amdgcn_rcpf(EA);
    float rB = __builtin_amdgcn_rcpf(EB);
    float4 res;
    res.x = (acc0A.x + acc0A.y) * rA;
    res.y = (acc1A.x + acc1A.y) * rA;
    res.z = (acc0B.x + acc0B.y) * rB;
    res.w = (acc1B.x + acc1B.y) * rB;
    ((float4*)&out[t * 4])[0] = res;
}

extern "C" void kernel_launch(void* const* d_in, const int* in_sizes, int n_in,
                              void* d_out, int out_size, void* d_ws, size_t ws_size,
                              hipStream_t stream) {
    const float* x   = (const float*)d_in[0];
    const float* W1  = (const float*)d_in[1];
    const float* b1  = (const float*)d_in[2];
    const float* W2  = (const float*)d_in[3];
    const float* b2  = (const float*)d_in[4];
    const float* Gw1 = (const float*)d_in[5];
    const float* Gb1 = (const float*)d_in[6];
    const float* Gw2 = (const float*)d_in[7];
    const float* Gb2 = (const float*)d_in[8];
    float* out = (float*)d_out;
    float* ws  = (float*)d_ws;   // 5120B f16 region + 2048B f32 gate region

    pack_kernel<<<1, 64, 0, stream>>>(W1, b1, W2, b2, Gw2, Gb2, ws);

    // 2 samples/thread -> 262144 threads -> 1024 blocks
    const int threads = 256;
    const int blocks = (524288 / 2) / threads;  // 1024
    moe_kernel<<<blocks, threads, 0, stream>>>(x, ws, Gw1, Gb1, out);
}